// Round 12
// baseline (259.799 us; speedup 1.0000x reference)
//
#include <hip/hip_runtime.h>

// A2M (LaneGCN map-agent attention) — MFMA + LDS-staged weights, 4-set batching.
// R12: each wave processes 64 rows/edges in 4 sets of 16 -> weight staging and
// barriers amortized 4x; edge grid ~489 blocks = single generation. Gathers
// pipelined one set ahead in phase 2. Same helpers as R10/R11.
// ws: xA bf16, xB f32, weight pool bf16, Ac bf16. Qc bf16 in d_out scratch.

typedef __attribute__((ext_vector_type(8))) short short8v;
typedef __attribute__((ext_vector_type(4))) float f32x4;

#define NXCD 8

// ---------------- scalar helpers ----------------
__device__ __forceinline__ unsigned short f2b(float f) {
    union { float f; unsigned u; } v; v.f = f;
    return (unsigned short)((v.u + 0x7fffu + ((v.u >> 16) & 1u)) >> 16);
}
__device__ __forceinline__ unsigned pk2(float a, float b) {
    return (unsigned)f2b(a) | ((unsigned)f2b(b) << 16);
}
__device__ __forceinline__ float bflo(unsigned u) { return __uint_as_float(u << 16); }
__device__ __forceinline__ float bfhi(unsigned u) { return __uint_as_float(u & 0xffff0000u); }

union U4S8 { unsigned u[4]; short8v v; };

// ---------------- LDS barrier that does NOT drain vmcnt ----------------
__device__ __forceinline__ void bar_lds() {
    __builtin_amdgcn_sched_barrier(0);
    asm volatile("s_waitcnt lgkmcnt(0)" ::: "memory");
    __builtin_amdgcn_s_barrier();
    __builtin_amdgcn_sched_barrier(0);
}

// ---------------- weight staging: global -> regs (early) -> LDS (late) ----------------
template<int NV>
__device__ __forceinline__ void sload(short8v (&v)[NV], const unsigned short* __restrict__ src,
                                      int t) {
#pragma unroll
    for (int i = 0; i < NV; i++) v[i] = *(const short8v*)(src + (size_t)i * 2048 + t * 8);
}
template<int NV>
__device__ __forceinline__ void swrite(unsigned short* dst, const short8v (&v)[NV], int t) {
#pragma unroll
    for (int i = 0; i < NV; i++) *(short8v*)(dst + i * 2048 + t * 8) = v[i];
}

// ---------------- wave GEMM from LDS weights ----------------
template<int NK>
__device__ __forceinline__ void wgemm_lds(const unsigned short* Wlds,
                                          const short8v* bf, f32x4 (&acc)[8], int l) {
#pragma unroll
    for (int mt = 0; mt < 8; mt++) {
        acc[mt] = (f32x4){0.f, 0.f, 0.f, 0.f};
#pragma unroll
        for (int kk = 0; kk < NK; kk++) {
            const short8v a = *(const short8v*)(Wlds + ((mt * NK + kk) * 64 + l) * 8);
            acc[mt] = __builtin_amdgcn_mfma_f32_16x16x32_bf16(a, bf[kk], acc[mt], 0, 0, 0);
        }
    }
}

// ---------------- in-register GN over 128 oc ----------------
__device__ __forceinline__ void gn_apply8(f32x4 (&acc)[8], const float* __restrict__ g,
                                          const float* __restrict__ b, int lg, bool relu) {
    float s = 0.f, s2 = 0.f;
#pragma unroll
    for (int mt = 0; mt < 8; mt++)
#pragma unroll
        for (int q = 0; q < 4; q++) { const float v = acc[mt][q]; s += v; s2 += v * v; }
    s += __shfl_xor(s, 16, 64); s2 += __shfl_xor(s2, 16, 64);
    s += __shfl_xor(s, 32, 64); s2 += __shfl_xor(s2, 32, 64);
    const float mu = s * (1.f / 128.f);
    const float rs = rsqrtf(s2 * (1.f / 128.f) - mu * mu + 1e-5f);
#pragma unroll
    for (int mt = 0; mt < 8; mt++) {
        const f32x4 g4 = *(const f32x4*)(g + mt * 16 + lg * 4);
        const f32x4 b4 = *(const f32x4*)(b + mt * 16 + lg * 4);
#pragma unroll
        for (int q = 0; q < 4; q++) {
            float y = (acc[mt][q] - mu) * rs * g4[q] + b4[q];
            acc[mt][q] = relu ? fmaxf(y, 0.f) : y;
        }
    }
}

__device__ __forceinline__ void pack_p(const f32x4 (&acc)[8], unsigned (&p)[8][2]) {
#pragma unroll
    for (int mt = 0; mt < 8; mt++) {
        p[mt][0] = pk2(acc[mt][0], acc[mt][1]);
        p[mt][1] = pk2(acc[mt][2], acc[mt][3]);
    }
}

// ---------------- per-wave LDS re-layout ----------------
__device__ __forceinline__ void lds_put(unsigned short* wbuf, const unsigned (&p)[8][2],
                                        int lg, int col) {
#pragma unroll
    for (int mt = 0; mt < 8; mt++) {
        const unsigned long long v = (unsigned long long)p[mt][0] |
                                     ((unsigned long long)p[mt][1] << 32);
        *(unsigned long long*)((char*)wbuf + ((col * 256 + mt * 32 + lg * 8) ^ ((col & 7) << 4))) = v;
    }
}
__device__ __forceinline__ void lds_wait() {
    asm volatile("s_waitcnt lgkmcnt(0)" ::: "memory");
    __builtin_amdgcn_sched_barrier(0);
}
__device__ __forceinline__ void lds_get(const unsigned short* wbuf, int lg, int col,
                                        short8v* bf) {
#pragma unroll
    for (int kk = 0; kk < 4; kk++)
        bf[kk] = *(const short8v*)((const char*)wbuf +
                 ((col * 256 + kk * 64 + lg * 16) ^ ((col & 7) << 4)));
}
__device__ __forceinline__ void relayout1(unsigned short* wbuf, int lg, int col,
                                          f32x4 (&acc)[8], short8v* bf) {
    unsigned p[8][2];
    pack_p(acc, p); lds_put(wbuf, p, lg, col); lds_wait(); lds_get(wbuf, lg, col, bf);
}

// ---------------- global row <-> frag helpers ----------------
__device__ __forceinline__ void load_bfrag_row(const float* __restrict__ src, int lg,
                                               short8v* bf) {
#pragma unroll
    for (int kk = 0; kk < 4; kk++) {
        const f32x4 a = *(const f32x4*)(src + kk * 32 + lg * 8);
        const f32x4 b = *(const f32x4*)(src + kk * 32 + lg * 8 + 4);
        U4S8 u;
        u.u[0] = pk2(a[0], a[1]); u.u[1] = pk2(a[2], a[3]);
        u.u[2] = pk2(b[0], b[1]); u.u[3] = pk2(b[2], b[3]);
        bf[kk] = u.v;
    }
}
__device__ __forceinline__ void store_rows(float* dst, const f32x4 (&acc)[8], int lg) {
#pragma unroll
    for (int mt = 0; mt < 8; mt++) *(f32x4*)(dst + mt * 16 + lg * 4) = acc[mt];
}
__device__ __forceinline__ void store_rows_bf16(unsigned short* dst, const f32x4 (&acc)[8], int lg) {
#pragma unroll
    for (int mt = 0; mt < 8; mt++) {
        uint2 u; u.x = pk2(acc[mt][0], acc[mt][1]); u.y = pk2(acc[mt][2], acc[mt][3]);
        *(uint2*)(dst + mt * 16 + lg * 4) = u;
    }
}
__device__ __forceinline__ void residual_add_bf16(f32x4 (&acc)[8],
                                                  const unsigned short* __restrict__ rp,
                                                  int lg, bool relu) {
#pragma unroll
    for (int mt = 0; mt < 8; mt++) {
        const uint2 u = *(const uint2*)(rp + mt * 16 + lg * 4);
        acc[mt][0] += bflo(u.x); acc[mt][1] += bfhi(u.x);
        acc[mt][2] += bflo(u.y); acc[mt][3] += bfhi(u.y);
        if (relu) {
#pragma unroll
            for (int q = 0; q < 4; q++) acc[mt][q] = fmaxf(acc[mt][q], 0.f);
        }
    }
}
__device__ __forceinline__ void gather_issue(const unsigned short* __restrict__ Qc,
                                             const unsigned short* __restrict__ Acp,
                                             int h, int w, int lg,
                                             uint2 (&qv)[8], uint2 (&av)[8]) {
    const int hl = (h < 0) ? 0 : h;
    const unsigned short* qp = Qc  + (size_t)hl * 128 + lg * 4;
    const unsigned short* ap = Acp + (size_t)w  * 128 + lg * 4;
#pragma unroll
    for (int mt = 0; mt < 8; mt++) {
        qv[mt] = *(const uint2*)(qp + mt * 16);
        av[mt] = *(const uint2*)(ap + mt * 16);
    }
}
__device__ __forceinline__ void gather_add(f32x4 (&acc)[8], const uint2 (&qv)[8],
                                           const uint2 (&av)[8]) {
#pragma unroll
    for (int mt = 0; mt < 8; mt++) {
        acc[mt][0] += bflo(qv[mt].x) + bflo(av[mt].x);
        acc[mt][1] += bfhi(qv[mt].x) + bfhi(av[mt].x);
        acc[mt][2] += bflo(qv[mt].y) + bflo(av[mt].y);
        acc[mt][3] += bfhi(qv[mt].y) + bfhi(av[mt].y);
    }
}
__device__ __forceinline__ void build_d1(const float* __restrict__ dw1,
                                         const float* __restrict__ db1,
                                         float dx, float dy, int lg, short8v* bf) {
#pragma unroll
    for (int kk = 0; kk < 4; kk++) {
        U4S8 u;
#pragma unroll
        for (int ii = 0; ii < 4; ii++) {
            const int c0 = kk * 32 + lg * 8 + ii * 2;
            const float2 wa = *(const float2*)(dw1 + 2 * c0);
            const float2 wb = *(const float2*)(dw1 + 2 * c0 + 2);
            const float2 bb = *(const float2*)(db1 + c0);
            u.u[ii] = pk2(fmaxf(fmaf(wa.x, dx, fmaf(wa.y, dy, bb.x)), 0.f),
                          fmaxf(fmaf(wb.x, dx, fmaf(wb.y, dy, bb.y)), 0.f));
        }
        bf[kk] = u.v;
    }
}

// ---------------- weight prep ----------------
struct PrepJob { const float* src; int dst; int ld; int kmax; int nk; };
struct PrepJobs { PrepJob j[17]; };

__global__ __launch_bounds__(64) void prep_weights(PrepJobs P, unsigned short* __restrict__ pool) {
    const PrepJob J = P.j[blockIdx.y];
    const int f = blockIdx.x;
    if (f >= 8 * J.nk) return;
    const int l = threadIdx.x;
    const int n = (f / J.nk) * 16 + (l & 15);
    const int kb = (f % J.nk) * 32 + (l >> 4) * 8;
    float v[8];
#pragma unroll
    for (int i = 0; i < 8; i++) {
        const int k = kb + i;
        v[i] = (k < J.kmax) ? J.src[(size_t)n * J.ld + k] : 0.f;
    }
    U4S8 u;
#pragma unroll
    for (int i = 0; i < 4; i++) u.u[i] = pk2(v[2 * i], v[2 * i + 1]);
    *(short8v*)(pool + J.dst + ((size_t)f * 64 + l) * 8) = u.v;
}

// -------- agent branch (4 sets) --------
__device__ __forceinline__ void agent_path(
    unsigned short* Wlds, int abid, int NA, const float* __restrict__ agents,
    const unsigned short* __restrict__ Wc1a, unsigned short* Ac,
    int t, int wid, int l, int lg, int col)
{
    short8v sv[8];
    sload<8>(sv, Wc1a, t);
    const int rbase = abid * 256 + wid * 64;
    short8v bf[4][4];
#pragma unroll
    for (int s = 0; s < 4; s++)
        load_bfrag_row(agents + (size_t)min(rbase + s * 16 + col, NA - 1) * 128, lg, bf[s]);
    swrite<8>(Wlds, sv, t);
    bar_lds();
    f32x4 acc[8];
#pragma unroll
    for (int s = 0; s < 4; s++) {
        const int r = rbase + s * 16 + col;
        wgemm_lds<4>(Wlds, bf[s], acc, l);
        if (r < NA) store_rows_bf16(Ac + (size_t)r * 128, acc, lg);
    }
}

// ---------------- K1: meta + node_pre(0) + agent(0) ----------------
__global__ __launch_bounds__(256, 2) void meta_node(
    const int N, const int NA, const int gN,
    const float* __restrict__ feat, const float* __restrict__ turn,
    const float* __restrict__ ctrl, const float* __restrict__ inter,
    const float* __restrict__ agents,
    const unsigned short* __restrict__ Wm,
    const float* __restrict__ mg, const float* __restrict__ mb,
    const unsigned short* __restrict__ Wagt, const unsigned short* __restrict__ Wq,
    const float* __restrict__ qg, const float* __restrict__ qb,
    const unsigned short* __restrict__ Wc1q, const unsigned short* __restrict__ Wc1a,
    unsigned short* __restrict__ xA, float* __restrict__ xB,
    unsigned short* __restrict__ Qc, unsigned short* __restrict__ Ac)
{
    __shared__ unsigned short Wlds[20480];
    __shared__ unsigned short wbuf[4][2048];
    const int t = threadIdx.x, wid = t >> 6, l = t & 63, lg = l >> 4, col = l & 15;
    if (blockIdx.x >= gN) {
        agent_path(Wlds, blockIdx.x - gN, NA, agents, Wc1a, Ac, t, wid, l, lg, col);
        return;
    }
    const int rbase = blockIdx.x * 256 + wid * 64;

    short8v s10[10];
    sload<10>(s10, Wm, t);
    short8v bf[4][5];
#pragma unroll
    for (int s = 0; s < 4; s++) {
        const int rc = min(rbase + s * 16 + col, N - 1);
        load_bfrag_row(feat + (size_t)rc * 128, lg, bf[s]);
        U4S8 u; u.u[0] = 0; u.u[1] = 0; u.u[2] = 0; u.u[3] = 0;
        if (lg == 0) {
            const float2 tv = *(const float2*)(turn + (size_t)rc * 2);
            u.u[0] = pk2(tv.x, tv.y);
            u.u[1] = pk2(ctrl[rc], inter[rc]);
        }
        bf[s][4] = u.v;
    }
    swrite<10>(Wlds, s10, t);
    bar_lds();

    short8v s8[8];
    sload<8>(s8, Wagt, t);
    f32x4 acc[8];
#pragma unroll
    for (int s = 0; s < 4; s++) {
        const int r = rbase + s * 16 + col;
        wgemm_lds<5>(Wlds, bf[s], acc, l);
        gn_apply8(acc, mg, mb, lg, true);
        if (r < N) store_rows_bf16(xA + (size_t)r * 128, acc, lg);
        relayout1(wbuf[wid], lg, col, acc, bf[s]);
    }
    bar_lds();
    swrite<8>(Wlds, s8, t);
    bar_lds();

    sload<8>(s8, Wq, t);
#pragma unroll
    for (int s = 0; s < 4; s++) {
        const int r = rbase + s * 16 + col;
        wgemm_lds<4>(Wlds, bf[s], acc, l);
        if (r < N) store_rows(xB + (size_t)r * 128, acc, lg);
    }
    bar_lds();
    swrite<8>(Wlds, s8, t);
    bar_lds();

    sload<8>(s8, Wc1q, t);
#pragma unroll
    for (int s = 0; s < 4; s++) {
        wgemm_lds<4>(Wlds, bf[s], acc, l);
        gn_apply8(acc, qg, qb, lg, true);
        relayout1(wbuf[wid], lg, col, acc, bf[s]);
    }
    bar_lds();
    swrite<8>(Wlds, s8, t);
    bar_lds();

#pragma unroll
    for (int s = 0; s < 4; s++) {
        const int r = rbase + s * 16 + col;
        wgemm_lds<4>(Wlds, bf[s], acc, l);
        if (r < N) store_rows_bf16(Qc + (size_t)r * 128, acc, lg);
    }
}

// ---------------- post phase helper ----------------
__device__ __forceinline__ void post_load_gn(const float* xp,
                                             const float* __restrict__ ng,
                                             const float* __restrict__ nb,
                                             int lg, short8v* bf) {
    float v[4][8];
    float s = 0.f, s2 = 0.f;
#pragma unroll
    for (int kk = 0; kk < 4; kk++) {
        *(f32x4*)(v[kk])     = *(const f32x4*)(xp + kk * 32 + lg * 8);
        *(f32x4*)(v[kk] + 4) = *(const f32x4*)(xp + kk * 32 + lg * 8 + 4);
#pragma unroll
        for (int i = 0; i < 8; i++) { s += v[kk][i]; s2 += v[kk][i] * v[kk][i]; }
    }
    s += __shfl_xor(s, 16, 64); s2 += __shfl_xor(s2, 16, 64);
    s += __shfl_xor(s, 32, 64); s2 += __shfl_xor(s2, 32, 64);
    const float mu = s * (1.f / 128.f);
    const float rs = rsqrtf(s2 * (1.f / 128.f) - mu * mu + 1e-5f);
#pragma unroll
    for (int kk = 0; kk < 4; kk++) {
        float y[8];
#pragma unroll
        for (int i = 0; i < 8; i += 4) {
            const f32x4 g4 = *(const f32x4*)(ng + kk * 32 + lg * 8 + i);
            const f32x4 b4 = *(const f32x4*)(nb + kk * 32 + lg * 8 + i);
#pragma unroll
            for (int q = 0; q < 4; q++)
                y[i + q] = fmaxf((v[kk][i + q] - mu) * rs * g4[q] + b4[q], 0.f);
        }
        U4S8 u;
#pragma unroll
        for (int i = 0; i < 4; i++) u.u[i] = pk2(y[2 * i], y[2 * i + 1]);
        bf[kk] = u.v;
    }
}

// ---------------- K3: post(i) + node_pre(i+1) + agent(i+1) ----------------
__global__ __launch_bounds__(256, 2) void post_node(
    const int N, const int NA, const int gN,
    const float* __restrict__ ng, const float* __restrict__ nb,
    const unsigned short* __restrict__ Wlin,
    const float* __restrict__ lgam, const float* __restrict__ lbet,
    const float* __restrict__ agents, const unsigned short* __restrict__ Wc1a,
    const unsigned short* __restrict__ Wagt, const unsigned short* __restrict__ Wq,
    const float* __restrict__ qg, const float* __restrict__ qb,
    const unsigned short* __restrict__ Wc1q,
    unsigned short* xA, float* xB,
    unsigned short* __restrict__ Qc, unsigned short* __restrict__ Ac)
{
    __shared__ unsigned short Wlds[16384];
    __shared__ unsigned short wbuf[4][2048];
    const int t = threadIdx.x, wid = t >> 6, l = t & 63, lg = l >> 4, col = l & 15;
    if (blockIdx.x >= gN) {
        agent_path(Wlds, blockIdx.x - gN, NA, agents, Wc1a, Ac, t, wid, l, lg, col);
        return;
    }
    const int rbase = blockIdx.x * 256 + wid * 64;

    short8v s8[8];
    sload<8>(s8, Wlin, t);
    short8v bf[4][4];
#pragma unroll
    for (int s = 0; s < 4; s++)
        post_load_gn(xB + (size_t)min(rbase + s * 16 + col, N - 1) * 128, ng, nb, lg, bf[s]);
    swrite<8>(Wlds, s8, t);
    bar_lds();

    sload<8>(s8, Wagt, t);
    f32x4 acc[8];
#pragma unroll
    for (int s = 0; s < 4; s++) {
        const int r = rbase + s * 16 + col;
        const int rc = min(r, N - 1);
        wgemm_lds<4>(Wlds, bf[s], acc, l);
        gn_apply8(acc, lgam, lbet, lg, false);
        residual_add_bf16(acc, xA + (size_t)rc * 128, lg, true);
        if (r < N) store_rows_bf16(xA + (size_t)r * 128, acc, lg);
        relayout1(wbuf[wid], lg, col, acc, bf[s]);
    }
    bar_lds();
    swrite<8>(Wlds, s8, t);
    bar_lds();

    sload<8>(s8, Wq, t);
#pragma unroll
    for (int s = 0; s < 4; s++) {
        const int r = rbase + s * 16 + col;
        wgemm_lds<4>(Wlds, bf[s], acc, l);
        if (r < N) store_rows(xB + (size_t)r * 128, acc, lg);
    }
    bar_lds();
    swrite<8>(Wlds, s8, t);
    bar_lds();

    sload<8>(s8, Wc1q, t);
#pragma unroll
    for (int s = 0; s < 4; s++) {
        wgemm_lds<4>(Wlds, bf[s], acc, l);
        gn_apply8(acc, qg, qb, lg, true);
        relayout1(wbuf[wid], lg, col, acc, bf[s]);
    }
    bar_lds();
    swrite<8>(Wlds, s8, t);
    bar_lds();

#pragma unroll
    for (int s = 0; s < 4; s++) {
        const int r = rbase + s * 16 + col;
        wgemm_lds<4>(Wlds, bf[s], acc, l);
        if (r < N) store_rows_bf16(Qc + (size_t)r * 128, acc, lg);
    }
}

// ---------------- K5: final post -> d_out ----------------
__global__ __launch_bounds__(256, 2) void post_final(
    const int N,
    const float* __restrict__ xB,
    const float* __restrict__ ng, const float* __restrict__ nb,
    const unsigned short* __restrict__ Wlin,
    const float* __restrict__ lgam, const float* __restrict__ lbet,
    const unsigned short* __restrict__ res, float* __restrict__ out)
{
    __shared__ unsigned short Wlds[16384];
    const int t = threadIdx.x, wid = t >> 6, l = t & 63, lg = l >> 4, col = l & 15;
    const int rbase = blockIdx.x * 256 + wid * 64;
    short8v s8[8];
    sload<8>(s8, Wlin, t);
    short8v bf[4][4];
#pragma unroll
    for (int s = 0; s < 4; s++)
        post_load_gn(xB + (size_t)min(rbase + s * 16 + col, N - 1) * 128, ng, nb, lg, bf[s]);
    swrite<8>(Wlds, s8, t);
    bar_lds();
    f32x4 acc[8];
#pragma unroll
    for (int s = 0; s < 4; s++) {
        const int r = rbase + s * 16 + col;
        const int rc = min(r, N - 1);
        wgemm_lds<4>(Wlds, bf[s], acc, l);
        gn_apply8(acc, lgam, lbet, lg, false);
        residual_add_bf16(acc, res + (size_t)rc * 128, lg, true);
        if (r < N) store_rows(out + (size_t)r * 128, acc, lg);
    }
}

// ---------------- edge ----------------
__global__ __launch_bounds__(256, 2) void edge_mfma(
    const int E, const int nwg,
    const int* __restrict__ hi, const int* __restrict__ wi,
    const float* __restrict__ mc, const float* __restrict__ ac,
    const float* __restrict__ dw1, const float* __restrict__ db1,
    const unsigned short* __restrict__ Wd2, const float* __restrict__ dg2, const float* __restrict__ db2,
    const unsigned short* __restrict__ Wc1d, const float* __restrict__ cg1, const float* __restrict__ cb1,
    const unsigned short* __restrict__ Wc2,
    const unsigned short* __restrict__ Qc, const unsigned short* __restrict__ Acp,
    float* __restrict__ OUT)
{
    __shared__ unsigned short Wlds[16384];
    __shared__ unsigned short wbuf[4][2048];
    __shared__ int s_h[256];
    const int t = threadIdx.x, wid = t >> 6, l = t & 63, lg = l >> 4, col = l & 15;

    int bid;
    {
        const int orig = blockIdx.x;
        const int q = nwg / NXCD, r = nwg % NXCD;
        const int xcd = orig % NXCD, i = orig / NXCD;
        bid = (xcd < r ? xcd * (q + 1) : r * (q + 1) + (xcd - r) * q) + i;
    }
    const int ebase = bid * 256 + wid * 64;

    short8v s8[8];
    sload<8>(s8, Wd2, t);

    int h4[4], w4[4];
    float dx4[4], dy4[4];
#pragma unroll
    for (int s = 0; s < 4; s++) {
        const int eidx = ebase + s * 16 + col;
        int h = -1, w = 0;
        if (eidx < E) { h = hi[eidx]; w = wi[eidx]; }
        h4[s] = h; w4[s] = w;
        if (lg == 0) s_h[wid * 64 + s * 16 + col] = h;
        const int hl = (h < 0) ? 0 : h;
        const float2 mcv = *(const float2*)(mc + 2 * (size_t)hl);
        const float2 acv = *(const float2*)(ac + 2 * (size_t)w);
        dx4[s] = mcv.x - acv.x; dy4[s] = mcv.y - acv.y;
    }

    swrite<8>(Wlds, s8, t);
    bar_lds();

    // ---- P1: d2 = relu(GN(d1 @ dw2^T)) for 4 sets ----
    sload<8>(s8, Wc1d, t);
    short8v bf2[4][4];
    f32x4 acc[8];
#pragma unroll
    for (int s = 0; s < 4; s++) {
        short8v bft[4];
        build_d1(dw1, db1, dx4[s], dy4[s], lg, bft);
        wgemm_lds<4>(Wlds, bft, acc, l);
        gn_apply8(acc, dg2, db2, lg, true);
        relayout1(wbuf[wid], lg, col, acc, bf2[s]);
    }
    bar_lds();
    swrite<8>(Wlds, s8, t);
    bar_lds();

    // ---- P2: c1 = relu(GN(d2 @ cw1_d^T + Qc[hi] + Ac[wi])), gathers 1-ahead ----
    sload<8>(s8, Wc2, t);
    uint2 qv[2][8], av[2][8];
    gather_issue(Qc, Acp, h4[0], w4[0], lg, qv[0], av[0]);
#pragma unroll
    for (int s = 0; s < 4; s++) {
        if (s < 3) gather_issue(Qc, Acp, h4[s + 1], w4[s + 1], lg, qv[(s + 1) & 1], av[(s + 1) & 1]);
        wgemm_lds<4>(Wlds, bf2[s], acc, l);
        gather_add(acc, qv[s & 1], av[s & 1]);
        gn_apply8(acc, cg1, cb1, lg, true);
        relayout1(wbuf[wid], lg, col, acc, bf2[s]);
    }
    bar_lds();
    swrite<8>(Wlds, s8, t);
    bar_lds();

    // ---- P3: c2 = c1 @ cw2^T + scatter (runs carried across sets) ----
    float p0 = 0.f, p1 = 0.f; int ph = -1;
#pragma unroll
    for (int s = 0; s < 4; s++) {
        wgemm_lds<4>(Wlds, bf2[s], acc, l);
        unsigned p[8][2];
        pack_p(acc, p); lds_put(wbuf[wid], p, lg, col); lds_wait();
#pragma unroll
        for (int e = 0; e < 16; e++) {
            const int he = s_h[wid * 64 + s * 16 + e];
            const unsigned short uA = *(const unsigned short*)((const char*)wbuf[wid] +
                                      ((e * 256 + l * 2) ^ ((e & 7) << 4)));
            const unsigned short uB = *(const unsigned short*)((const char*)wbuf[wid] +
                                      ((e * 256 + (64 + l) * 2) ^ ((e & 7) << 4)));
            const float vA = __uint_as_float((unsigned)uA << 16);
            const float vB = __uint_as_float((unsigned)uB << 16);
            if (he == ph) { p0 += vA; p1 += vB; }
            else {
                if (ph >= 0) {
                    atomicAdd(&OUT[(size_t)ph * 128 + l], p0);
                    atomicAdd(&OUT[(size_t)ph * 128 + 64 + l], p1);
                }
                ph = he; p0 = vA; p1 = vB;
            }
        }
    }
    if (ph >= 0) {
        atomicAdd(&OUT[(size_t)ph * 128 + l], p0);
        atomicAdd(&OUT[(size_t)ph * 128 + 64 + l], p1);
    }
}

extern "C" void kernel_launch(void* const* d_in, const int* in_sizes, int n_in,
                              void* d_out, int out_size, void* d_ws, size_t ws_size,
                              hipStream_t stream)
{
    const float* feat    = (const float*)d_in[0];
    const float* turn    = (const float*)d_in[1];
    const float* ctrl    = (const float*)d_in[2];
    const float* inter   = (const float*)d_in[3];
    const float* agents  = (const float*)d_in[4];
    const float* mc      = (const float*)d_in[5];
    const float* ac      = (const float*)d_in[6];
    const float* meta_w  = (const float*)d_in[7];
    const float* meta_g  = (const float*)d_in[8];
    const float* meta_b  = (const float*)d_in[9];
    const float* dist_w1 = (const float*)d_in[10];
    const float* dist_b1 = (const float*)d_in[11];
    const float* dist_w2 = (const float*)d_in[12];
    const float* dist_g2 = (const float*)d_in[13];
    const float* dist_b2 = (const float*)d_in[14];
    const float* query_w = (const float*)d_in[15];
    const float* query_g = (const float*)d_in[16];
    const float* query_b = (const float*)d_in[17];
    const float* ctx_w1  = (const float*)d_in[18];
    const float* ctx_g1  = (const float*)d_in[19];
    const float* ctx_b1  = (const float*)d_in[20];
    const float* ctx_w2  = (const float*)d_in[21];
    const float* agt_w   = (const float*)d_in[22];
    const float* norm_g  = (const float*)d_in[23];
    const float* norm_b  = (const float*)d_in[24];
    const float* lin_w   = (const float*)d_in[25];
    const float* lin_g   = (const float*)d_in[26];
    const float* lin_b   = (const float*)d_in[27];
    const int*   hi      = (const int*)d_in[28];
    const int*   wi      = (const int*)d_in[29];

    const int E  = in_sizes[28];
    const int N  = in_sizes[0] / 128;   // 64000
    const int NA = in_sizes[4] / 128;   // 2048

    unsigned short* xA = (unsigned short*)d_ws;                 // bf16 N*128
    float* xB = (float*)(xA + (size_t)N * 128);                 // f32  N*128
    unsigned short* pool = (unsigned short*)(xB + (size_t)N * 128);

    const int FR128  = 8 * 4 * 64 * 8;
    const int FRMETA = 8 * 5 * 64 * 8;
    const int POOL_ELEMS = FRMETA + 16 * FR128;

    unsigned short* Ac = pool + POOL_ELEMS;
    unsigned short* Qc = (unsigned short*)d_out;

    PrepJobs P;
    P.j[0] = { meta_w, 0, 132, 132, 5 };
    for (int i = 0; i < 2; i++) {
        const int b = FRMETA + i * 8 * FR128;
        P.j[1 + i * 8 + 0] = { query_w + (size_t)i * 16384, b + 0 * FR128, 128, 128, 4 };
        P.j[1 + i * 8 + 1] = { agt_w   + (size_t)i * 16384, b + 1 * FR128, 128, 128, 4 };
        P.j[1 + i * 8 + 2] = { dist_w2 + (size_t)i * 16384, b + 2 * FR128, 128, 128, 4 };
        P.j[1 + i * 8 + 3] = { ctx_w1  + (size_t)i * 49152,       b + 3 * FR128, 384, 128, 4 };
        P.j[1 + i * 8 + 4] = { ctx_w1  + (size_t)i * 49152 + 128, b + 4 * FR128, 384, 128, 4 };
        P.j[1 + i * 8 + 5] = { ctx_w2  + (size_t)i * 16384, b + 5 * FR128, 128, 128, 4 };
        P.j[1 + i * 8 + 6] = { lin_w   + (size_t)i * 16384, b + 6 * FR128, 128, 128, 4 };
        P.j[1 + i * 8 + 7] = { ctx_w1  + (size_t)i * 49152 + 256, b + 7 * FR128, 384, 128, 4 };
    }
    prep_weights<<<dim3(40, 17), 64, 0, stream>>>(P, pool);

    const int gN = (N + 255) / 256;
    const int gA = (NA + 255) / 256;
    const int gE = (E + 255) / 256;

    const unsigned short* W0 = pool + FRMETA;
    const unsigned short* W1 = pool + FRMETA + 8 * FR128;

    meta_node<<<gN + gA, 256, 0, stream>>>(
        N, NA, gN, feat, turn, ctrl, inter, agents,
        pool, meta_g, meta_b,
        W0 + 1 * FR128, W0 + 0 * FR128, query_g, query_b,
        W0 + 4 * FR128, W0 + 7 * FR128,
        xA, xB, Qc, Ac);

    edge_mfma<<<gE, 256, 0, stream>>>(
        E, gE, hi, wi, mc, ac,
        dist_w1, dist_b1,
        W0 + 2 * FR128, dist_g2, dist_b2,
        W0 + 3 * FR128, ctx_g1, ctx_b1,
        W0 + 5 * FR128, Qc, Ac, xB);

    post_node<<<gN + gA, 256, 0, stream>>>(
        N, NA, gN,
        norm_g, norm_b, W0 + 6 * FR128, lin_g, lin_b,
        agents, W1 + 7 * FR128,
        W1 + 1 * FR128, W1 + 0 * FR128, query_g + 128, query_b + 128,
        W1 + 4 * FR128,
        xA, xB, Qc, Ac);

    edge_mfma<<<gE, 256, 0, stream>>>(
        E, gE, hi, wi, mc, ac,
        dist_w1 + 256, dist_b1 + 128,
        W1 + 2 * FR128, dist_g2 + 128, dist_b2 + 128,
        W1 + 3 * FR128, ctx_g1 + 128, ctx_b1 + 128,
        W1 + 5 * FR128, Qc, Ac, xB);

    post_final<<<gN, 256, 0, stream>>>(
        N, xB, norm_g + 128, norm_b + 128,
        W1 + 6 * FR128, lin_g + 128, lin_b + 128, xA, (float*)d_out);
}

// Round 13
// 191.660 us; speedup vs baseline: 1.3555x; 1.3555x over previous
//
#include <hip/hip_runtime.h>

// A2M (LaneGCN map-agent attention) — MFMA + LDS-staged weights.
// R13: wbuf eliminated — relayout & scatter staging reuse Wlds (dead after its
// single GEMM) via per-wave 4KB slices + one extra barrier. Edge LDS 33KB ->
// target 4 blocks/CU (was 2 at 49.6KB). 1 set/wave (R12's 4-set spilled).
// ws: xA bf16, xB f32, weight pool bf16, Ac bf16. Qc bf16 in d_out scratch.

typedef __attribute__((ext_vector_type(8))) short short8v;
typedef __attribute__((ext_vector_type(4))) float f32x4;

#define NXCD 8

// ---------------- scalar helpers ----------------
__device__ __forceinline__ unsigned short f2b(float f) {
    union { float f; unsigned u; } v; v.f = f;
    return (unsigned short)((v.u + 0x7fffu + ((v.u >> 16) & 1u)) >> 16);
}
__device__ __forceinline__ unsigned pk2(float a, float b) {
    return (unsigned)f2b(a) | ((unsigned)f2b(b) << 16);
}
__device__ __forceinline__ float bflo(unsigned u) { return __uint_as_float(u << 16); }
__device__ __forceinline__ float bfhi(unsigned u) { return __uint_as_float(u & 0xffff0000u); }

union U4S8 { unsigned u[4]; short8v v; };

// ---------------- LDS barrier that does NOT drain vmcnt ----------------
__device__ __forceinline__ void bar_lds() {
    __builtin_amdgcn_sched_barrier(0);
    asm volatile("s_waitcnt lgkmcnt(0)" ::: "memory");
    __builtin_amdgcn_s_barrier();
    __builtin_amdgcn_sched_barrier(0);
}

// ---------------- weight staging: global -> regs (early) -> LDS (late) ----------------
template<int NV>
__device__ __forceinline__ void sload(short8v (&v)[NV], const unsigned short* __restrict__ src,
                                      int t) {
#pragma unroll
    for (int i = 0; i < NV; i++) v[i] = *(const short8v*)(src + (size_t)i * 2048 + t * 8);
}
template<int NV>
__device__ __forceinline__ void swrite(unsigned short* dst, const short8v (&v)[NV], int t) {
#pragma unroll
    for (int i = 0; i < NV; i++) *(short8v*)(dst + i * 2048 + t * 8) = v[i];
}

// ---------------- wave GEMM from LDS weights ----------------
template<int NK>
__device__ __forceinline__ void wgemm_lds(const unsigned short* Wlds,
                                          const short8v* bf, f32x4 (&acc)[8], int l) {
#pragma unroll
    for (int mt = 0; mt < 8; mt++) {
        acc[mt] = (f32x4){0.f, 0.f, 0.f, 0.f};
#pragma unroll
        for (int kk = 0; kk < NK; kk++) {
            const short8v a = *(const short8v*)(Wlds + ((mt * NK + kk) * 64 + l) * 8);
            acc[mt] = __builtin_amdgcn_mfma_f32_16x16x32_bf16(a, bf[kk], acc[mt], 0, 0, 0);
        }
    }
}

// ---------------- in-register GN over 128 oc ----------------
__device__ __forceinline__ void gn_apply8(f32x4 (&acc)[8], const float* __restrict__ g,
                                          const float* __restrict__ b, int lg, bool relu) {
    float s = 0.f, s2 = 0.f;
#pragma unroll
    for (int mt = 0; mt < 8; mt++)
#pragma unroll
        for (int q = 0; q < 4; q++) { const float v = acc[mt][q]; s += v; s2 += v * v; }
    s += __shfl_xor(s, 16, 64); s2 += __shfl_xor(s2, 16, 64);
    s += __shfl_xor(s, 32, 64); s2 += __shfl_xor(s2, 32, 64);
    const float mu = s * (1.f / 128.f);
    const float rs = rsqrtf(s2 * (1.f / 128.f) - mu * mu + 1e-5f);
#pragma unroll
    for (int mt = 0; mt < 8; mt++) {
        const f32x4 g4 = *(const f32x4*)(g + mt * 16 + lg * 4);
        const f32x4 b4 = *(const f32x4*)(b + mt * 16 + lg * 4);
#pragma unroll
        for (int q = 0; q < 4; q++) {
            float y = (acc[mt][q] - mu) * rs * g4[q] + b4[q];
            acc[mt][q] = relu ? fmaxf(y, 0.f) : y;
        }
    }
}

__device__ __forceinline__ void pack_p(const f32x4 (&acc)[8], unsigned (&p)[8][2]) {
#pragma unroll
    for (int mt = 0; mt < 8; mt++) {
        p[mt][0] = pk2(acc[mt][0], acc[mt][1]);
        p[mt][1] = pk2(acc[mt][2], acc[mt][3]);
    }
}

// ---------------- per-wave LDS re-layout (into a 4KB slice) ----------------
__device__ __forceinline__ void lds_put(unsigned short* wslice, const unsigned (&p)[8][2],
                                        int lg, int col) {
#pragma unroll
    for (int mt = 0; mt < 8; mt++) {
        const unsigned long long v = (unsigned long long)p[mt][0] |
                                     ((unsigned long long)p[mt][1] << 32);
        *(unsigned long long*)((char*)wslice + ((col * 256 + mt * 32 + lg * 8) ^ ((col & 7) << 4))) = v;
    }
}
__device__ __forceinline__ void lds_wait() {
    asm volatile("s_waitcnt lgkmcnt(0)" ::: "memory");
    __builtin_amdgcn_sched_barrier(0);
}
__device__ __forceinline__ void lds_get(const unsigned short* wslice, int lg, int col,
                                        short8v* bf) {
#pragma unroll
    for (int kk = 0; kk < 4; kk++)
        bf[kk] = *(const short8v*)((const char*)wslice +
                 ((col * 256 + kk * 64 + lg * 16) ^ ((col & 7) << 4)));
}
__device__ __forceinline__ void relayout1(unsigned short* wslice, int lg, int col,
                                          f32x4 (&acc)[8], short8v* bf) {
    unsigned p[8][2];
    pack_p(acc, p); lds_put(wslice, p, lg, col); lds_wait(); lds_get(wslice, lg, col, bf);
}

// ---------------- global row <-> frag helpers ----------------
__device__ __forceinline__ void load_bfrag_row(const float* __restrict__ src, int lg,
                                               short8v* bf) {
#pragma unroll
    for (int kk = 0; kk < 4; kk++) {
        const f32x4 a = *(const f32x4*)(src + kk * 32 + lg * 8);
        const f32x4 b = *(const f32x4*)(src + kk * 32 + lg * 8 + 4);
        U4S8 u;
        u.u[0] = pk2(a[0], a[1]); u.u[1] = pk2(a[2], a[3]);
        u.u[2] = pk2(b[0], b[1]); u.u[3] = pk2(b[2], b[3]);
        bf[kk] = u.v;
    }
}
__device__ __forceinline__ void store_rows(float* dst, const f32x4 (&acc)[8], int lg) {
#pragma unroll
    for (int mt = 0; mt < 8; mt++) *(f32x4*)(dst + mt * 16 + lg * 4) = acc[mt];
}
__device__ __forceinline__ void store_rows_bf16(unsigned short* dst, const f32x4 (&acc)[8], int lg) {
#pragma unroll
    for (int mt = 0; mt < 8; mt++) {
        uint2 u; u.x = pk2(acc[mt][0], acc[mt][1]); u.y = pk2(acc[mt][2], acc[mt][3]);
        *(uint2*)(dst + mt * 16 + lg * 4) = u;
    }
}
__device__ __forceinline__ void residual_add_bf16(f32x4 (&acc)[8],
                                                  const unsigned short* __restrict__ rp,
                                                  int lg, bool relu) {
#pragma unroll
    for (int mt = 0; mt < 8; mt++) {
        const uint2 u = *(const uint2*)(rp + mt * 16 + lg * 4);
        acc[mt][0] += bflo(u.x); acc[mt][1] += bfhi(u.x);
        acc[mt][2] += bflo(u.y); acc[mt][3] += bfhi(u.y);
        if (relu) {
#pragma unroll
            for (int q = 0; q < 4; q++) acc[mt][q] = fmaxf(acc[mt][q], 0.f);
        }
    }
}
__device__ __forceinline__ void gather_issue(const unsigned short* __restrict__ Qc,
                                             const unsigned short* __restrict__ Acp,
                                             int h, int w, int lg,
                                             uint2 (&qv)[8], uint2 (&av)[8]) {
    const int hl = (h < 0) ? 0 : h;
    const unsigned short* qp = Qc  + (size_t)hl * 128 + lg * 4;
    const unsigned short* ap = Acp + (size_t)w  * 128 + lg * 4;
#pragma unroll
    for (int mt = 0; mt < 8; mt++) {
        qv[mt] = *(const uint2*)(qp + mt * 16);
        av[mt] = *(const uint2*)(ap + mt * 16);
    }
}
__device__ __forceinline__ void gather_add(f32x4 (&acc)[8], const uint2 (&qv)[8],
                                           const uint2 (&av)[8]) {
#pragma unroll
    for (int mt = 0; mt < 8; mt++) {
        acc[mt][0] += bflo(qv[mt].x) + bflo(av[mt].x);
        acc[mt][1] += bfhi(qv[mt].x) + bfhi(av[mt].x);
        acc[mt][2] += bflo(qv[mt].y) + bflo(av[mt].y);
        acc[mt][3] += bfhi(qv[mt].y) + bfhi(av[mt].y);
    }
}
__device__ __forceinline__ void build_d1(const float* __restrict__ dw1,
                                         const float* __restrict__ db1,
                                         float dx, float dy, int lg, short8v* bf) {
#pragma unroll
    for (int kk = 0; kk < 4; kk++) {
        U4S8 u;
#pragma unroll
        for (int ii = 0; ii < 4; ii++) {
            const int c0 = kk * 32 + lg * 8 + ii * 2;
            const float2 wa = *(const float2*)(dw1 + 2 * c0);
            const float2 wb = *(const float2*)(dw1 + 2 * c0 + 2);
            const float2 bb = *(const float2*)(db1 + c0);
            u.u[ii] = pk2(fmaxf(fmaf(wa.x, dx, fmaf(wa.y, dy, bb.x)), 0.f),
                          fmaxf(fmaf(wb.x, dx, fmaf(wb.y, dy, bb.y)), 0.f));
        }
        bf[kk] = u.v;
    }
}

// ---------------- weight prep ----------------
struct PrepJob { const float* src; int dst; int ld; int kmax; int nk; };
struct PrepJobs { PrepJob j[17]; };

__global__ __launch_bounds__(64) void prep_weights(PrepJobs P, unsigned short* __restrict__ pool) {
    const PrepJob J = P.j[blockIdx.y];
    const int f = blockIdx.x;
    if (f >= 8 * J.nk) return;
    const int l = threadIdx.x;
    const int n = (f / J.nk) * 16 + (l & 15);
    const int kb = (f % J.nk) * 32 + (l >> 4) * 8;
    float v[8];
#pragma unroll
    for (int i = 0; i < 8; i++) {
        const int k = kb + i;
        v[i] = (k < J.kmax) ? J.src[(size_t)n * J.ld + k] : 0.f;
    }
    U4S8 u;
#pragma unroll
    for (int i = 0; i < 4; i++) u.u[i] = pk2(v[2 * i], v[2 * i + 1]);
    *(short8v*)(pool + J.dst + ((size_t)f * 64 + l) * 8) = u.v;
}

// -------- agent branch body --------
__device__ __forceinline__ void agent_path(
    unsigned short* Wlds, int abid, int NA, const float* __restrict__ agents,
    const unsigned short* __restrict__ Wc1a, unsigned short* Ac,
    int t, int wid, int l, int lg, int col)
{
    short8v sv[8];
    sload<8>(sv, Wc1a, t);
    const int r = abid * 64 + wid * 16 + col;
    const int rc = min(r, NA - 1);
    short8v bf[4];
    load_bfrag_row(agents + (size_t)rc * 128, lg, bf);
    swrite<8>(Wlds, sv, t);
    bar_lds();
    f32x4 acc[8];
    wgemm_lds<4>(Wlds, bf, acc, l);
    if (r < NA) store_rows_bf16(Ac + (size_t)r * 128, acc, lg);
}

// ---------------- K1: meta + node_pre(0) + agent(0) ----------------
__global__ __launch_bounds__(256, 2) void meta_node(
    const int N, const int NA, const int gN,
    const float* __restrict__ feat, const float* __restrict__ turn,
    const float* __restrict__ ctrl, const float* __restrict__ inter,
    const float* __restrict__ agents,
    const unsigned short* __restrict__ Wm,
    const float* __restrict__ mg, const float* __restrict__ mb,
    const unsigned short* __restrict__ Wagt, const unsigned short* __restrict__ Wq,
    const float* __restrict__ qg, const float* __restrict__ qb,
    const unsigned short* __restrict__ Wc1q, const unsigned short* __restrict__ Wc1a,
    unsigned short* __restrict__ xA, float* __restrict__ xB,
    unsigned short* __restrict__ Qc, unsigned short* __restrict__ Ac)
{
    __shared__ unsigned short Wlds[20480];   // 40KB: meta W / later 32KB Ws / relayout slices
    const int t = threadIdx.x, wid = t >> 6, l = t & 63, lg = l >> 4, col = l & 15;
    unsigned short* wslice = Wlds + wid * 2048;
    if (blockIdx.x >= gN) {
        agent_path(Wlds, blockIdx.x - gN, NA, agents, Wc1a, Ac, t, wid, l, lg, col);
        return;
    }
    const int r = blockIdx.x * 64 + wid * 16 + col;
    const int rc = min(r, N - 1);

    short8v s10[10];
    sload<10>(s10, Wm, t);
    short8v bf[5];
    load_bfrag_row(feat + (size_t)rc * 128, lg, bf);
    {
        U4S8 u; u.u[0] = 0; u.u[1] = 0; u.u[2] = 0; u.u[3] = 0;
        if (lg == 0) {
            const float2 tv = *(const float2*)(turn + (size_t)rc * 2);
            u.u[0] = pk2(tv.x, tv.y);
            u.u[1] = pk2(ctrl[rc], inter[rc]);
        }
        bf[4] = u.v;
    }
    swrite<10>(Wlds, s10, t);
    bar_lds();

    short8v s8[8];
    sload<8>(s8, Wagt, t);
    f32x4 acc[8];
    wgemm_lds<5>(Wlds, bf, acc, l);
    gn_apply8(acc, mg, mb, lg, true);
    if (r < N) store_rows_bf16(xA + (size_t)r * 128, acc, lg);
    bar_lds();                                // all waves done reading Wm
    short8v bx[4];
    relayout1(wslice, lg, col, acc, bx);      // reuse Wlds region
    bar_lds();                                // relayout reads done
    swrite<8>(Wlds, s8, t);
    bar_lds();

    sload<8>(s8, Wq, t);
    wgemm_lds<4>(Wlds, bx, acc, l);
    if (r < N) store_rows(xB + (size_t)r * 128, acc, lg);
    bar_lds();
    swrite<8>(Wlds, s8, t);
    bar_lds();

    sload<8>(s8, Wc1q, t);
    wgemm_lds<4>(Wlds, bx, acc, l);
    gn_apply8(acc, qg, qb, lg, true);
    bar_lds();
    relayout1(wslice, lg, col, acc, bx);
    bar_lds();
    swrite<8>(Wlds, s8, t);
    bar_lds();

    wgemm_lds<4>(Wlds, bx, acc, l);
    if (r < N) store_rows_bf16(Qc + (size_t)r * 128, acc, lg);
}

// ---------------- post phase helper ----------------
__device__ __forceinline__ void post_load_gn(const float* xp,
                                             const float* __restrict__ ng,
                                             const float* __restrict__ nb,
                                             int lg, short8v* bf) {
    float v[4][8];
    float s = 0.f, s2 = 0.f;
#pragma unroll
    for (int kk = 0; kk < 4; kk++) {
        *(f32x4*)(v[kk])     = *(const f32x4*)(xp + kk * 32 + lg * 8);
        *(f32x4*)(v[kk] + 4) = *(const f32x4*)(xp + kk * 32 + lg * 8 + 4);
#pragma unroll
        for (int i = 0; i < 8; i++) { s += v[kk][i]; s2 += v[kk][i] * v[kk][i]; }
    }
    s += __shfl_xor(s, 16, 64); s2 += __shfl_xor(s2, 16, 64);
    s += __shfl_xor(s, 32, 64); s2 += __shfl_xor(s2, 32, 64);
    const float mu = s * (1.f / 128.f);
    const float rs = rsqrtf(s2 * (1.f / 128.f) - mu * mu + 1e-5f);
#pragma unroll
    for (int kk = 0; kk < 4; kk++) {
        float y[8];
#pragma unroll
        for (int i = 0; i < 8; i += 4) {
            const f32x4 g4 = *(const f32x4*)(ng + kk * 32 + lg * 8 + i);
            const f32x4 b4 = *(const f32x4*)(nb + kk * 32 + lg * 8 + i);
#pragma unroll
            for (int q = 0; q < 4; q++)
                y[i + q] = fmaxf((v[kk][i + q] - mu) * rs * g4[q] + b4[q], 0.f);
        }
        U4S8 u;
#pragma unroll
        for (int i = 0; i < 4; i++) u.u[i] = pk2(y[2 * i], y[2 * i + 1]);
        bf[kk] = u.v;
    }
}

// ---------------- K3: post(i) + node_pre(i+1) + agent(i+1) ----------------
__global__ __launch_bounds__(256, 2) void post_node(
    const int N, const int NA, const int gN,
    const float* __restrict__ ng, const float* __restrict__ nb,
    const unsigned short* __restrict__ Wlin,
    const float* __restrict__ lgam, const float* __restrict__ lbet,
    const float* __restrict__ agents, const unsigned short* __restrict__ Wc1a,
    const unsigned short* __restrict__ Wagt, const unsigned short* __restrict__ Wq,
    const float* __restrict__ qg, const float* __restrict__ qb,
    const unsigned short* __restrict__ Wc1q,
    unsigned short* xA, float* xB,
    unsigned short* __restrict__ Qc, unsigned short* __restrict__ Ac)
{
    __shared__ unsigned short Wlds[16384];   // 32KB
    const int t = threadIdx.x, wid = t >> 6, l = t & 63, lg = l >> 4, col = l & 15;
    unsigned short* wslice = Wlds + wid * 2048;
    if (blockIdx.x >= gN) {
        agent_path(Wlds, blockIdx.x - gN, NA, agents, Wc1a, Ac, t, wid, l, lg, col);
        return;
    }
    const int r = blockIdx.x * 64 + wid * 16 + col;
    const int rc = min(r, N - 1);

    short8v s8[8];
    sload<8>(s8, Wlin, t);
    short8v bf[4];
    post_load_gn(xB + (size_t)rc * 128, ng, nb, lg, bf);
    swrite<8>(Wlds, s8, t);
    bar_lds();

    sload<8>(s8, Wagt, t);
    f32x4 acc[8];
    wgemm_lds<4>(Wlds, bf, acc, l);
    gn_apply8(acc, lgam, lbet, lg, false);
    residual_add_bf16(acc, xA + (size_t)rc * 128, lg, true);
    if (r < N) store_rows_bf16(xA + (size_t)r * 128, acc, lg);
    bar_lds();
    short8v bx[4];
    relayout1(wslice, lg, col, acc, bx);
    bar_lds();
    swrite<8>(Wlds, s8, t);
    bar_lds();

    sload<8>(s8, Wq, t);
    wgemm_lds<4>(Wlds, bx, acc, l);
    if (r < N) store_rows(xB + (size_t)r * 128, acc, lg);
    bar_lds();
    swrite<8>(Wlds, s8, t);
    bar_lds();

    sload<8>(s8, Wc1q, t);
    wgemm_lds<4>(Wlds, bx, acc, l);
    gn_apply8(acc, qg, qb, lg, true);
    bar_lds();
    relayout1(wslice, lg, col, acc, bx);
    bar_lds();
    swrite<8>(Wlds, s8, t);
    bar_lds();

    wgemm_lds<4>(Wlds, bx, acc, l);
    if (r < N) store_rows_bf16(Qc + (size_t)r * 128, acc, lg);
}

// ---------------- K5: final post -> d_out ----------------
__global__ __launch_bounds__(256, 2) void post_final(
    const int N,
    const float* __restrict__ xB,
    const float* __restrict__ ng, const float* __restrict__ nb,
    const unsigned short* __restrict__ Wlin,
    const float* __restrict__ lgam, const float* __restrict__ lbet,
    const unsigned short* __restrict__ res, float* __restrict__ out)
{
    __shared__ unsigned short Wlds[16384];
    const int t = threadIdx.x, wid = t >> 6, l = t & 63, lg = l >> 4, col = l & 15;
    const int r = blockIdx.x * 64 + wid * 16 + col;
    const int rc = min(r, N - 1);
    short8v s8[8];
    sload<8>(s8, Wlin, t);
    short8v bf[4];
    post_load_gn(xB + (size_t)rc * 128, ng, nb, lg, bf);
    swrite<8>(Wlds, s8, t);
    bar_lds();
    f32x4 acc[8];
    wgemm_lds<4>(Wlds, bf, acc, l);
    gn_apply8(acc, lgam, lbet, lg, false);
    residual_add_bf16(acc, res + (size_t)rc * 128, lg, true);
    if (r < N) store_rows(out + (size_t)r * 128, acc, lg);
}

// ---------------- edge ----------------
__global__ __launch_bounds__(256, 2) void edge_mfma(
    const int E, const int nwg,
    const int* __restrict__ hi, const int* __restrict__ wi,
    const float* __restrict__ mc, const float* __restrict__ ac,
    const float* __restrict__ dw1, const float* __restrict__ db1,
    const unsigned short* __restrict__ Wd2, const float* __restrict__ dg2, const float* __restrict__ db2,
    const unsigned short* __restrict__ Wc1d, const float* __restrict__ cg1, const float* __restrict__ cb1,
    const unsigned short* __restrict__ Wc2,
    const unsigned short* __restrict__ Qc, const unsigned short* __restrict__ Acp,
    float* __restrict__ OUT)
{
    __shared__ unsigned short Wlds[16384];   // 32KB, also hosts relayout + scatter slices
    __shared__ int s_h[64];
    const int t = threadIdx.x, wid = t >> 6, l = t & 63, lg = l >> 4, col = l & 15;
    unsigned short* wslice = Wlds + wid * 2048;

    int bid;
    {
        const int orig = blockIdx.x;
        const int q = nwg / NXCD, r = nwg % NXCD;
        const int xcd = orig % NXCD, i = orig / NXCD;
        bid = (xcd < r ? xcd * (q + 1) : r * (q + 1) + (xcd - r) * q) + i;
    }
    const int eidx = bid * 64 + wid * 16 + col;

    short8v s8[8];
    sload<8>(s8, Wd2, t);

    int h = -1, w = 0;
    if (eidx < E) { h = hi[eidx]; w = wi[eidx]; }
    if (lg == 0) s_h[wid * 16 + col] = h;
    const int hl = (h < 0) ? 0 : h;
    const float2 mcv = *(const float2*)(mc + 2 * (size_t)hl);
    const float2 acv = *(const float2*)(ac + 2 * (size_t)w);
    const float dx = mcv.x - acv.x, dy = mcv.y - acv.y;

    // gathers issued now; stay on vmcnt across bar_lds, consumed after GEMM2
    uint2 qv[8], av[8];
    gather_issue(Qc, Acp, h, w, lg, qv, av);

    short8v bf[4];
    build_d1(dw1, db1, dx, dy, lg, bf);

    swrite<8>(Wlds, s8, t);
    bar_lds();

    sload<8>(s8, Wc1d, t);
    f32x4 acc[8];
    wgemm_lds<4>(Wlds, bf, acc, l);
    gn_apply8(acc, dg2, db2, lg, true);
    bar_lds();                                // Wd2 dead across all waves
    relayout1(wslice, lg, col, acc, bf);
    bar_lds();
    swrite<8>(Wlds, s8, t);
    bar_lds();

    sload<8>(s8, Wc2, t);
    wgemm_lds<4>(Wlds, bf, acc, l);
    gather_add(acc, qv, av);
    gn_apply8(acc, cg1, cb1, lg, true);
    bar_lds();                                // Wc1d dead
    relayout1(wslice, lg, col, acc, bf);
    bar_lds();
    swrite<8>(Wlds, s8, t);
    bar_lds();

    wgemm_lds<4>(Wlds, bf, acc, l);
    bar_lds();                                // Wc2 dead -> scatter staging may clobber
    unsigned p[8][2];
    pack_p(acc, p); lds_put(wslice, p, lg, col); lds_wait();

    // scatter: 2 channel passes (l, 64+l), run-combined over 16 sorted-hi edges
#pragma unroll
    for (int pass = 0; pass < 2; pass++) {
        const int c = pass * 64 + l;
        float pend = 0.f; int ph = -1;
#pragma unroll
        for (int e = 0; e < 16; e++) {
            const int he = s_h[wid * 16 + e];
            const unsigned short uv = *(const unsigned short*)((const char*)wslice +
                                      ((e * 256 + c * 2) ^ ((e & 7) << 4)));
            const float v = __uint_as_float((unsigned)uv << 16);
            if (he == ph) pend += v;
            else {
                if (ph >= 0) atomicAdd(&OUT[(size_t)ph * 128 + c], pend);
                ph = he; pend = v;
            }
        }
        if (ph >= 0) atomicAdd(&OUT[(size_t)ph * 128 + c], pend);
    }
}

extern "C" void kernel_launch(void* const* d_in, const int* in_sizes, int n_in,
                              void* d_out, int out_size, void* d_ws, size_t ws_size,
                              hipStream_t stream)
{
    const float* feat    = (const float*)d_in[0];
    const float* turn    = (const float*)d_in[1];
    const float* ctrl    = (const float*)d_in[2];
    const float* inter   = (const float*)d_in[3];
    const float* agents  = (const float*)d_in[4];
    const float* mc      = (const float*)d_in[5];
    const float* ac      = (const float*)d_in[6];
    const float* meta_w  = (const float*)d_in[7];
    const float* meta_g  = (const float*)d_in[8];
    const float* meta_b  = (const float*)d_in[9];
    const float* dist_w1 = (const float*)d_in[10];
    const float* dist_b1 = (const float*)d_in[11];
    const float* dist_w2 = (const float*)d_in[12];
    const float* dist_g2 = (const float*)d_in[13];
    const float* dist_b2 = (const float*)d_in[14];
    const float* query_w = (const float*)d_in[15];
    const float* query_g = (const float*)d_in[16];
    const float* query_b = (const float*)d_in[17];
    const float* ctx_w1  = (const float*)d_in[18];
    const float* ctx_g1  = (const float*)d_in[19];
    const float* ctx_b1  = (const float*)d_in[20];
    const float* ctx_w2  = (const float*)d_in[21];
    const float* agt_w   = (const float*)d_in[22];
    const float* norm_g  = (const float*)d_in[23];
    const float* norm_b  = (const float*)d_in[24];
    const float* lin_w   = (const float*)d_in[25];
    const float* lin_g   = (const float*)d_in[26];
    const float* lin_b   = (const float*)d_in[27];
    const int*   hi      = (const int*)d_in[28];
    const int*   wi      = (const int*)d_in[29];

    const int E  = in_sizes[28];
    const int N  = in_sizes[0] / 128;   // 64000
    const int NA = in_sizes[4] / 128;   // 2048

    unsigned short* xA = (unsigned short*)d_ws;                 // bf16 N*128
    float* xB = (float*)(xA + (size_t)N * 128);                 // f32  N*128
    unsigned short* pool = (unsigned short*)(xB + (size_t)N * 128);

    const int FR128  = 8 * 4 * 64 * 8;
    const int FRMETA = 8 * 5 * 64 * 8;
    const int POOL_ELEMS = FRMETA + 16 * FR128;

    unsigned short* Ac = pool + POOL_ELEMS;
    unsigned short* Qc = (unsigned short*)d_out;

    PrepJobs P;
    P.j[0] = { meta_w, 0, 132, 132, 5 };
    for (int i = 0; i < 2; i++) {
        const int b = FRMETA + i * 8 * FR128;
        P.j[1 + i * 8 + 0] = { query_w + (size_t)i * 16384, b + 0 * FR128, 128, 128, 4 };
        P.j[1 + i * 8 + 1] = { agt_w   + (size_t)i * 16384, b + 1 * FR128, 128, 128, 4 };
        P.j[1 + i * 8 + 2] = { dist_w2 + (size_t)i * 16384, b + 2 * FR128, 128, 128, 4 };
        P.j[1 + i * 8 + 3] = { ctx_w1  + (size_t)i * 49152,       b + 3 * FR128, 384, 128, 4 };
        P.j[1 + i * 8 + 4] = { ctx_w1  + (size_t)i * 49152 + 128, b + 4 * FR128, 384, 128, 4 };
        P.j[1 + i * 8 + 5] = { ctx_w2  + (size_t)i * 16384, b + 5 * FR128, 128, 128, 4 };
        P.j[1 + i * 8 + 6] = { lin_w   + (size_t)i * 16384, b + 6 * FR128, 128, 128, 4 };
        P.j[1 + i * 8 + 7] = { ctx_w1  + (size_t)i * 49152 + 256, b + 7 * FR128, 384, 128, 4 };
    }
    prep_weights<<<dim3(40, 17), 64, 0, stream>>>(P, pool);

    const int gN = (N + 63) / 64;
    const int gA = (NA + 63) / 64;
    const int gE = (E + 63) / 64;

    const unsigned short* W0 = pool + FRMETA;
    const unsigned short* W1 = pool + FRMETA + 8 * FR128;

    meta_node<<<gN + gA, 256, 0, stream>>>(
        N, NA, gN, feat, turn, ctrl, inter, agents,
        pool, meta_g, meta_b,
        W0 + 1 * FR128, W0 + 0 * FR128, query_g, query_b,
        W0 + 4 * FR128, W0 + 7 * FR128,
        xA, xB, Qc, Ac);

    edge_mfma<<<gE, 256, 0, stream>>>(
        E, gE, hi, wi, mc, ac,
        dist_w1, dist_b1,
        W0 + 2 * FR128, dist_g2, dist_b2,
        W0 + 3 * FR128, ctx_g1, ctx_b1,
        W0 + 5 * FR128, Qc, Ac, xB);

    post_node<<<gN + gA, 256, 0, stream>>>(
        N, NA, gN,
        norm_g, norm_b, W0 + 6 * FR128, lin_g, lin_b,
        agents, W1 + 7 * FR128,
        W1 + 1 * FR128, W1 + 0 * FR128, query_g + 128, query_b + 128,
        W1 + 4 * FR128,
        xA, xB, Qc, Ac);

    edge_mfma<<<gE, 256, 0, stream>>>(
        E, gE, hi, wi, mc, ac,
        dist_w1 + 256, dist_b1 + 128,
        W1 + 2 * FR128, dist_g2 + 128, dist_b2 + 128,
        W1 + 3 * FR128, ctx_g1 + 128, ctx_b1 + 128,
        W1 + 5 * FR128, Qc, Ac, xB);

    post_final<<<gN, 256, 0, stream>>>(
        N, xB, norm_g + 128, norm_b + 128,
        W1 + 6 * FR128, lin_g + 128, lin_b + 128, xA, (float*)d_out);
}